// Round 1
// baseline (866.537 us; speedup 1.0000x reference)
//
#include <hip/hip_runtime.h>
#include <math.h>

// Sizes (fixed for this problem)
#define NB   8
#define HH   64
#define NC   128
#define NHID 512
#define NL   4096   // HH*HH

__device__ __forceinline__ float gelu_f(float v) {
  return 0.5f * v * (1.f + erff(v * 0.70710678118654752f));
}
__device__ __forceinline__ float sigmoid_f(float v) {
  return 1.f / (1.f + expf(-v));
}

// ---------------- LayerNorm over C=128 (4 rows / block, 1 wave / row) ----------------
__global__ __launch_bounds__(256) void ln_kernel(const float* __restrict__ x,
    const float* __restrict__ g, const float* __restrict__ bb, float* __restrict__ out) {
  int row = blockIdx.x * 4 + (threadIdx.x >> 6);
  int lane = threadIdx.x & 63;
  size_t base = (size_t)row * NC;
  float v0 = x[base + lane], v1 = x[base + lane + 64];
  float s = v0 + v1, ss = v0 * v0 + v1 * v1;
#pragma unroll
  for (int off = 32; off > 0; off >>= 1) {
    s  += __shfl_down(s, off);
    ss += __shfl_down(ss, off);
  }
  s = __shfl(s, 0); ss = __shfl(ss, 0);
  float mean = s * (1.f / NC);
  float var  = ss * (1.f / NC) - mean * mean;
  float rstd = rsqrtf(var + 1e-5f);
  out[base + lane]      = (v0 - mean) * rstd * g[lane]      + bb[lane];
  out[base + lane + 64] = (v1 - mean) * rstd * g[lane + 64] + bb[lane + 64];
}

// ---------------- T: per (b,win,cin) masked window sums (mean-of-conv trick) ----------------
// T[i,j] = sum over rows R_i, cols C_j of the 32x32 window; R_0=[0,30],R_1=[0,31],R_2=[1,31]
__global__ __launch_bounds__(64) void t_kernel(const float* __restrict__ xln, float* __restrict__ T) {
  int blk = blockIdx.x;           // (b*4+win)*128 + cin
  int cin = blk & 127;
  int bw  = blk >> 7;             // b*4+win
  int win = bw & 3, b = bw >> 2;
  int hw = win >> 1, wwn = win & 1;
  int l = threadIdx.x;
  int cc = l & 31;                // column within window (fixed per thread)
  const float* base = xln + (((size_t)(b * 64 + hw * 32)) * 64 + wwn * 32) * NC + cin;
  float A = 0, r0 = 0, r31 = 0, c0 = 0, c31 = 0;
#pragma unroll
  for (int k = 0; k < 16; ++k) {
    int p = l + 64 * k;           // spatial index r*32+cc
    int r = p >> 5;
    float v = base[((size_t)r * 64 + cc) * NC];
    A += v;
    if (r == 0)   r0  += v;
    if (r == 31)  r31 += v;
    if (cc == 0)  c0  += v;
    if (cc == 31) c31 += v;
  }
#pragma unroll
  for (int off = 32; off > 0; off >>= 1) {
    A   += __shfl_down(A, off);
    r0  += __shfl_down(r0, off);
    r31 += __shfl_down(r31, off);
    c0  += __shfl_down(c0, off);
    c31 += __shfl_down(c31, off);
  }
  if (l == 0) {
    float x00 = base[0];
    float x0c = base[(size_t)31 * NC];                    // row0,col31
    float xr0 = base[((size_t)31 * 64) * NC];             // row31,col0
    float xrc = base[((size_t)31 * 64 + 31) * NC];        // row31,col31
    float* t = T + (size_t)blk * 9;
    t[0] = A - r31 - c31 + xrc;   // i=0,j=0
    t[1] = A - r31;               // i=0,j=1
    t[2] = A - r31 - c0 + xr0;    // i=0,j=2
    t[3] = A - c31;               // i=1,j=0
    t[4] = A;                     // i=1,j=1
    t[5] = A - c0;                // i=1,j=2
    t[6] = A - r0 - c31 + x0c;    // i=2,j=0
    t[7] = A - r0;                // i=2,j=1
    t[8] = A - r0 - c0 + x00;     // i=2,j=2
  }
}

// ---------------- SE dot: ydot[b,g] = sum_cout w_down[g,cout] * sum_{cin,ij} conv1_w*T ----------------
__global__ __launch_bounds__(256) void se_dot_kernel(const float* __restrict__ T,
    const float* __restrict__ conv1_w, const float* __restrict__ w_down, float* __restrict__ ydot) {
  int bg = blockIdx.x;            // b*4+g
  int g = bg & 3;
  int t = threadIdx.x;
  int cout = t >> 1, half = t & 1;
  const float* wp = conv1_w + (size_t)(g * NC + cout) * 1152 + half * 576;
  const float* tp = T + (size_t)bg * 1152 + half * 576;
  float acc = 0;
  for (int i = 0; i < 576; ++i) acc += wp[i] * tp[i];
  acc *= w_down[g * NC + cout];
#pragma unroll
  for (int off = 32; off > 0; off >>= 1) acc += __shfl_down(acc, off);
  __shared__ float red[4];
  if ((t & 63) == 0) red[t >> 6] = acc;
  __syncthreads();
  if (t == 0) ydot[bg] = red[0] + red[1] + red[2] + red[3];
}

// ---------------- tiny SE MLP -> wgt[b,g] ----------------
__global__ void mlp_kernel(const float* __restrict__ ydot, const float* __restrict__ b_down,
    const float* __restrict__ w1, const float* __restrict__ b1,
    const float* __restrict__ w2, const float* __restrict__ b2, float* __restrict__ wgt) {
  int b = threadIdx.x;
  if (b >= NB) return;
  float y[4];
#pragma unroll
  for (int g = 0; g < 4; ++g) y[g] = ydot[b * 4 + g] * (1.f / 1024.f) + b_down[g];
  float y1[16];
#pragma unroll
  for (int i = 0; i < 16; ++i) {
    float a = b1[i];
#pragma unroll
    for (int g = 0; g < 4; ++g) a += y[g] * w1[i * 4 + g];
    y1[i] = gelu_f(a);
  }
#pragma unroll
  for (int g = 0; g < 4; ++g) {
    float a = b2[g];
#pragma unroll
    for (int i = 0; i < 16; ++i) a += y1[i] * w2[g * 16 + i];
    wgt[b * 4 + g] = sigmoid_f(a);
  }
}

// ---------------- G[w,q,p,ij] = sum_cin w_gk[q, w*C+cin] * conv1_w[w*C+p, cin, ij] ----------------
__global__ __launch_bounds__(128) void g_kernel(const float* __restrict__ conv1_w,
    const float* __restrict__ w_gk, float* __restrict__ G) {
  int blk = blockIdx.x;           // w*128 + q
  int w = blk >> 7;
  int q = blk & 127;
  int p = threadIdx.x;
  __shared__ float wg[128];
  wg[p] = w_gk[(size_t)q * 512 + w * NC + p];
  __syncthreads();
  const float* cw = conv1_w + (size_t)(w * NC + p) * 1152;
  float acc[9] = {0, 0, 0, 0, 0, 0, 0, 0, 0};
  for (int cin = 0; cin < 128; ++cin) {
    float s = wg[cin];
#pragma unroll
    for (int ij = 0; ij < 9; ++ij) acc[ij] += s * cw[cin * 9 + ij];
  }
  float* gp = G + ((size_t)blk * 128 + p) * 9;
#pragma unroll
  for (int ij = 0; ij < 9; ++ij) gp[ij] = acc[ij];
}

// ---------------- sfus[o] = sum_p w_fus[o, 512+p] ----------------
__global__ void sfus_kernel(const float* __restrict__ w_fus, float* __restrict__ sfus) {
  int o = threadIdx.x;
  float s = 0;
  for (int p = 0; p < 128; ++p) s += w_fus[(size_t)o * 640 + 512 + p];
  sfus[o] = s;
}

// ---------------- AW[w,o,q,ij] = A1 + A2 ----------------
__global__ __launch_bounds__(128) void aw_kernel(const float* __restrict__ conv1_w,
    const float* __restrict__ w_fus, const float* __restrict__ G, float* __restrict__ AW) {
  int blk = blockIdx.x;           // w*128 + o
  int w = blk >> 7;
  int o = blk & 127;
  int q = threadIdx.x;
  __shared__ float wf1[128], wf2[128];
  wf1[q] = w_fus[(size_t)o * 640 + w * NC + q];
  wf2[q] = w_fus[(size_t)o * 640 + 512 + q];
  __syncthreads();
  float acc[9] = {0, 0, 0, 0, 0, 0, 0, 0, 0};
  // A1: sum_c w_fus[o, w*C+c] * conv1_w[w*C+c, q, ij]
  for (int c = 0; c < 128; ++c) {
    const float* cw = conv1_w + ((size_t)(w * NC + c) * NC + q) * 9;
    float s = wf1[c];
#pragma unroll
    for (int ij = 0; ij < 9; ++ij) acc[ij] += s * cw[ij];
  }
  // A2: sum_p w_fus[o, 512+p] * G[w,q,p,ij]
  const float* gq = G + (size_t)(w * NC + q) * 128 * 9;
  for (int p = 0; p < 128; ++p) {
    float s = wf2[p];
#pragma unroll
    for (int ij = 0; ij < 9; ++ij) acc[ij] += s * gq[p * 9 + ij];
  }
  float* ap = AW + ((size_t)(w * NC + o) * NC + q) * 9;
#pragma unroll
  for (int ij = 0; ij < 9; ++ij) ap[ij] = acc[ij];
}

// ---------------- M[b,o,q,ij] = sum_w wgt[b,w]*AW[w,o,q,ij] + sfus[o]*b_gk[q] ----------------
__global__ __launch_bounds__(128) void m_kernel(const float* __restrict__ AW,
    const float* __restrict__ wgt, const float* __restrict__ sfus,
    const float* __restrict__ b_gk, float* __restrict__ M) {
  int blk = blockIdx.x;           // b*128 + o
  int b = blk >> 7;
  int o = blk & 127;
  int q = threadIdx.x;
  float w0 = wgt[b * 4 + 0], w1v = wgt[b * 4 + 1], w2v = wgt[b * 4 + 2], w3v = wgt[b * 4 + 3];
  float a3 = sfus[o] * b_gk[q];
  float* mp = M + ((size_t)blk * NC + q) * 9;
  const size_t ws_stride = (size_t)NC * NC * 9;  // 147456
#pragma unroll
  for (int ij = 0; ij < 9; ++ij) {
    size_t idx = ((size_t)o * NC + q) * 9 + ij;
    mp[ij] = w0 * AW[idx] + w1v * AW[idx + ws_stride] + w2v * AW[idx + 2 * ws_stride]
           + w3v * AW[idx + 3 * ws_stride] + a3;
  }
}

// ---------------- per-sample 3x3 conv (effective filter M[b]) + b_fus + residual ----------------
// block: 8x8 spatial tile x all 128 oc; thread: 4 spatial x 8 oc
__global__ __launch_bounds__(256) void conv_kernel(const float* __restrict__ x0,
    const float* __restrict__ xln, const float* __restrict__ M,
    const float* __restrict__ b_fus, float* __restrict__ xout) {
  __shared__ float XT[100 * 129];
  int b = blockIdx.x >> 6;
  int tile = blockIdx.x & 63;
  int y0 = (tile >> 3) * 8, xx0 = (tile & 7) * 8;
  int tid = threadIdx.x;
  // stage 10x10x128 with zero pad; [row][col] stride 129 over q
  for (int idx = tid; idx < 12800; idx += 256) {
    int q = idx & 127, rc = idx >> 7;
    int row = rc / 10, col = rc - row * 10;
    int gy = y0 + row - 1, gx = xx0 + col - 1;
    float v = 0.f;
    if (gy >= 0 && gy < 64 && gx >= 0 && gx < 64)
      v = xln[(((size_t)b * NL) + gy * 64 + gx) * NC + q];
    XT[rc * 129 + q] = v;
  }
  __syncthreads();
  int oi = tid >> 4, si = tid & 15;
  int ob = oi * 8;
  float acc[4][8];
#pragma unroll
  for (int k = 0; k < 4; ++k)
#pragma unroll
    for (int j = 0; j < 8; ++j) acc[k][j] = 0.f;
  const float* Mb = M + (size_t)b * NC * NC * 9;
#pragma unroll
  for (int ij = 0; ij < 9; ++ij) {
    int di = ij / 3, dj = ij - di * 3;
    int lofs[4];
#pragma unroll
    for (int k = 0; k < 4; ++k) {
      int sp = si * 4 + k;
      int rs = (sp >> 3) + di, cs = (sp & 7) + dj;
      lofs[k] = (rs * 10 + cs) * 129;
    }
    const float* mp = Mb + (size_t)ob * 1152 + ij;
    for (int q = 0; q < 128; ++q) {
      float xv[4];
#pragma unroll
      for (int k = 0; k < 4; ++k) xv[k] = XT[lofs[k] + q];
#pragma unroll
      for (int j = 0; j < 8; ++j) {
        float f = mp[(size_t)j * 1152 + q * 9];
#pragma unroll
        for (int k = 0; k < 4; ++k) acc[k][j] += xv[k] * f;
      }
    }
  }
#pragma unroll
  for (int k = 0; k < 4; ++k) {
    int sp = si * 4 + k;
    int gy = y0 + (sp >> 3), gx = xx0 + (sp & 7);
    size_t base = (((size_t)b * NL) + gy * 64 + gx) * NC + ob;
#pragma unroll
    for (int j = 0; j < 8; ++j)
      xout[base + j] = x0[base + j] + acc[k][j] + b_fus[ob + j];
  }
}

// ---------------- lin1 + gelu (one 128-col chunk of HID) ----------------
__global__ __launch_bounds__(256) void lin1_kernel(const float* __restrict__ xin,
    const float* __restrict__ w, const float* __restrict__ bias,
    float* __restrict__ hout, int h0) {
  __shared__ float XT[64 * 129];
  int rb = blockIdx.x * 64;
  int tid = threadIdx.x;
  for (int idx = tid; idx < 8192; idx += 256) {
    int q = idx & 127, r = idx >> 7;
    XT[r * 129 + q] = xin[((size_t)(rb + r)) * NC + q];
  }
  __syncthreads();
  int oi = tid >> 4, si = tid & 15;
  int ob = oi * 8;
  float acc[4][8];
#pragma unroll
  for (int k = 0; k < 4; ++k)
#pragma unroll
    for (int j = 0; j < 8; ++j) acc[k][j] = 0.f;
  const float* wp = w + (size_t)(h0 + ob) * NC;
  for (int q = 0; q < 128; ++q) {
    float xv[4];
#pragma unroll
    for (int k = 0; k < 4; ++k) xv[k] = XT[(si * 4 + k) * 129 + q];
#pragma unroll
    for (int j = 0; j < 8; ++j) {
      float f = wp[(size_t)j * NC + q];
#pragma unroll
      for (int k = 0; k < 4; ++k) acc[k][j] += xv[k] * f;
    }
  }
#pragma unroll
  for (int k = 0; k < 4; ++k) {
#pragma unroll
    for (int j = 0; j < 8; ++j) {
      float v = acc[k][j] + bias[h0 + ob + j];
      hout[((size_t)(rb + si * 4 + k)) * 128 + ob + j] = gelu_f(v);
    }
  }
}

// ---------------- depthwise 3x3 + bias + gelu on a 128-chunk ----------------
__global__ __launch_bounds__(256) void dw_kernel(const float* __restrict__ h1,
    const float* __restrict__ dw_w, const float* __restrict__ dw_b,
    float* __restrict__ h2, int h0) {
  int idx = blockIdx.x * 256 + threadIdx.x;   // [0, 8*4096*128)
  int hc = idx & 127;
  int s  = idx >> 7;                          // [0, 32768)
  int xw = s & 63, yy = (s >> 6) & 63;
  const float* wp = dw_w + (size_t)(h0 + hc) * 9;
  float wv[9];
#pragma unroll
  for (int ij = 0; ij < 9; ++ij) wv[ij] = wp[ij];
  float a = dw_b[h0 + hc];
#pragma unroll
  for (int di = -1; di <= 1; ++di) {
    int y2 = yy + di;
    if (y2 < 0 || y2 > 63) continue;
#pragma unroll
    for (int dj = -1; dj <= 1; ++dj) {
      int x2 = xw + dj;
      if (x2 < 0 || x2 > 63) continue;
      a += wv[(di + 1) * 3 + (dj + 1)] * h1[((size_t)(s + di * 64 + dj)) * 128 + hc];
    }
  }
  h2[idx] = gelu_f(a);
}

// ---------------- lin2 partial accumulate into out (+xattn+bias on chunk 0) ----------------
__global__ __launch_bounds__(256) void lin2_kernel(const float* __restrict__ h2,
    const float* __restrict__ w, const float* __restrict__ bias,
    const float* __restrict__ xres, float* __restrict__ out, int h0) {
  __shared__ float XT[64 * 129];
  int rb = blockIdx.x * 64;
  int tid = threadIdx.x;
  for (int idx = tid; idx < 8192; idx += 256) {
    int q = idx & 127, r = idx >> 7;
    XT[r * 129 + q] = h2[((size_t)(rb + r)) * 128 + q];
  }
  __syncthreads();
  int oi = tid >> 4, si = tid & 15;
  int ob = oi * 8;
  float acc[4][8];
#pragma unroll
  for (int k = 0; k < 4; ++k)
#pragma unroll
    for (int j = 0; j < 8; ++j) acc[k][j] = 0.f;
  const float* wp = w + (size_t)ob * NHID + h0;
  for (int q = 0; q < 128; ++q) {
    float xv[4];
#pragma unroll
    for (int k = 0; k < 4; ++k) xv[k] = XT[(si * 4 + k) * 129 + q];
#pragma unroll
    for (int j = 0; j < 8; ++j) {
      float f = wp[(size_t)j * NHID + q];
#pragma unroll
      for (int k = 0; k < 4; ++k) acc[k][j] += xv[k] * f;
    }
  }
#pragma unroll
  for (int k = 0; k < 4; ++k) {
#pragma unroll
    for (int j = 0; j < 8; ++j) {
      size_t gi = ((size_t)(rb + si * 4 + k)) * NC + ob + j;
      float base = (h0 == 0) ? (xres[gi] + bias[ob + j]) : out[gi];
      out[gi] = base + acc[k][j];
    }
  }
}

extern "C" void kernel_launch(void* const* d_in, const int* in_sizes, int n_in,
                              void* d_out, int out_size, void* d_ws, size_t ws_size,
                              hipStream_t stream) {
  (void)in_sizes; (void)n_in; (void)out_size; (void)ws_size;
  const float* x       = (const float*)d_in[0];
  const float* ln1_g   = (const float*)d_in[1];
  const float* ln1_b   = (const float*)d_in[2];
  const float* conv1_w = (const float*)d_in[3];
  const float* w_down  = (const float*)d_in[4];
  const float* b_down  = (const float*)d_in[5];
  const float* w1      = (const float*)d_in[6];
  const float* b1      = (const float*)d_in[7];
  const float* w2      = (const float*)d_in[8];
  const float* b2      = (const float*)d_in[9];
  const float* w_gk    = (const float*)d_in[10];
  const float* b_gk    = (const float*)d_in[11];
  const float* w_fus   = (const float*)d_in[12];
  const float* b_fus   = (const float*)d_in[13];
  const float* ln2_g   = (const float*)d_in[14];
  const float* ln2_b   = (const float*)d_in[15];
  const float* lin1_w  = (const float*)d_in[16];
  const float* lin1_b  = (const float*)d_in[17];
  const float* dw_w    = (const float*)d_in[18];
  const float* dw_b    = (const float*)d_in[19];
  const float* lin2_w  = (const float*)d_in[20];
  const float* lin2_b  = (const float*)d_in[21];
  float* out = (float*)d_out;
  float* ws  = (float*)d_ws;

  // ws layout (floats); total ~23.37M floats (~89.2 MiB)
  float* xln  = ws;                 // 4194304
  float* xatt = ws + 4194304;       // 4194304
  float* xln2 = ws + 8388608;       // 4194304
  float* h1c  = ws + 12582912;      // 4194304
  float* h2c  = ws + 16777216;      // 4194304
  float* Tb   = ws + 20971520;      // 36864
  float* wgtb = ws + 21008384;      // 32
  float* ydot = ws + 21008416;      // 32
  float* sfus = ws + 21008448;      // 128
  float* Gb   = ws + 21008576;      // 589824
  float* AWb  = ws + 21598400;      // 589824
  float* Mb   = ws + 22188224;      // 1179648

  ln_kernel<<<8192, 256, 0, stream>>>(x, ln1_g, ln1_b, xln);
  t_kernel<<<4096, 64, 0, stream>>>(xln, Tb);
  se_dot_kernel<<<32, 256, 0, stream>>>(Tb, conv1_w, w_down, ydot);
  mlp_kernel<<<1, 64, 0, stream>>>(ydot, b_down, w1, b1, w2, b2, wgtb);
  g_kernel<<<512, 128, 0, stream>>>(conv1_w, w_gk, Gb);
  sfus_kernel<<<1, 128, 0, stream>>>(w_fus, sfus);
  aw_kernel<<<512, 128, 0, stream>>>(conv1_w, w_fus, Gb, AWb);
  m_kernel<<<1024, 128, 0, stream>>>(AWb, wgtb, sfus, b_gk, Mb);
  conv_kernel<<<512, 256, 0, stream>>>(x, xln, Mb, b_fus, xatt);
  ln_kernel<<<8192, 256, 0, stream>>>(xatt, ln2_g, ln2_b, xln2);
  for (int h0 = 0; h0 < NHID; h0 += 128) {
    lin1_kernel<<<512, 256, 0, stream>>>(xln2, lin1_w, lin1_b, h1c, h0);
    dw_kernel<<<16384, 256, 0, stream>>>(h1c, dw_w, dw_b, h2c, h0);
    lin2_kernel<<<512, 256, 0, stream>>>(h2c, lin2_w, lin2_b, xatt, out, h0);
  }
}

// Round 2
// 317.605 us; speedup vs baseline: 2.7284x; 2.7284x over previous
//
#include <hip/hip_runtime.h>
#include <math.h>

#define NB   8
#define HH   64
#define NC   128
#define NHID 512
#define NL   4096

typedef __attribute__((ext_vector_type(4))) float f32x4;
typedef __attribute__((ext_vector_type(8))) __bf16 bf16x8;

__device__ __forceinline__ float gelu_f(float v) {
  return 0.5f * v * (1.f + erff(v * 0.70710678118654752f));
}
__device__ __forceinline__ float sigmoid_f(float v) {
  return 1.f / (1.f + expf(-v));
}
__device__ __forceinline__ unsigned short f2bf(float f) {
  unsigned int u = __builtin_bit_cast(unsigned int, f);
  unsigned int r = (u + 0x7FFFu + ((u >> 16) & 1u)) >> 16;
  return (unsigned short)r;
}
__device__ __forceinline__ float bf2f(unsigned short h) {
  return __builtin_bit_cast(float, ((unsigned int)h) << 16);
}
__device__ __forceinline__ float bflo(unsigned int w) {
  return __builtin_bit_cast(float, w << 16);
}
__device__ __forceinline__ float bfhi(unsigned int w) {
  return __builtin_bit_cast(float, w & 0xFFFF0000u);
}
// async global->LDS, 16B per lane; lds dest wave-uniform base (+ lane*16 by HW)
__device__ __forceinline__ void gld16(const void* g, void* l) {
  __builtin_amdgcn_global_load_lds(
      (const __attribute__((address_space(1))) unsigned int*)g,
      (__attribute__((address_space(3))) unsigned int*)l, 16, 0, 0);
}

// ---------------- LayerNorm -> packed bf16 (optionally XOR-swizzled rows) ----------------
template<bool SWZ>
__global__ __launch_bounds__(256) void ln_kernel(const float* __restrict__ x,
    const float* __restrict__ g, const float* __restrict__ bb, unsigned short* __restrict__ out) {
  int wv = threadIdx.x >> 6, l = threadIdx.x & 63;
  int row = blockIdx.x * 4 + wv;
  const float2 v = *(const float2*)(x + (size_t)row * NC + l * 2);
  float s = v.x + v.y, ss = v.x * v.x + v.y * v.y;
#pragma unroll
  for (int off = 32; off > 0; off >>= 1) {
    s  += __shfl_down(s, off);
    ss += __shfl_down(ss, off);
  }
  s = __shfl(s, 0); ss = __shfl(ss, 0);
  float mean = s * (1.f / NC);
  float rstd = rsqrtf(ss * (1.f / NC) - mean * mean + 1e-5f);
  const float2 gg = *(const float2*)(g + l * 2);
  const float2 bv = *(const float2*)(bb + l * 2);
  float o0 = (v.x - mean) * rstd * gg.x + bv.x;
  float o1 = (v.y - mean) * rstd * gg.y + bv.y;
  unsigned int pk = (unsigned int)f2bf(o0) | ((unsigned int)f2bf(o1) << 16);
  int c16 = l >> 2;
  int cs = SWZ ? (c16 ^ (row & 7)) : c16;
  *(unsigned int*)((char*)out + (size_t)row * 256 + (cs << 4) + (l & 3) * 4) = pk;
}

// ---------------- T: masked window sums from bf16 xln ----------------
__global__ __launch_bounds__(64) void t_kernel(const unsigned short* __restrict__ xln, float* __restrict__ T) {
  int blk = blockIdx.x;
  int cin = blk & 127;
  int bw  = blk >> 7;
  int win = bw & 3, b = bw >> 2;
  int hw = win >> 1, wwn = win & 1;
  int l = threadIdx.x;
  int cc = l & 31;
  const unsigned short* base = xln + (((size_t)(b * 64 + hw * 32)) * 64 + wwn * 32) * NC + cin;
  float A = 0, r0 = 0, r31 = 0, c0 = 0, c31 = 0;
#pragma unroll
  for (int k = 0; k < 16; ++k) {
    int p = l + 64 * k;
    int r = p >> 5;
    float v = bf2f(base[((size_t)r * 64 + cc) * NC]);
    A += v;
    if (r == 0)   r0  += v;
    if (r == 31)  r31 += v;
    if (cc == 0)  c0  += v;
    if (cc == 31) c31 += v;
  }
#pragma unroll
  for (int off = 32; off > 0; off >>= 1) {
    A   += __shfl_down(A, off);
    r0  += __shfl_down(r0, off);
    r31 += __shfl_down(r31, off);
    c0  += __shfl_down(c0, off);
    c31 += __shfl_down(c31, off);
  }
  if (l == 0) {
    float x00 = bf2f(base[0]);
    float x0c = bf2f(base[(size_t)31 * NC]);
    float xr0 = bf2f(base[((size_t)31 * 64) * NC]);
    float xrc = bf2f(base[((size_t)31 * 64 + 31) * NC]);
    float* t = T + (size_t)blk * 9;
    t[0] = A - r31 - c31 + xrc;
    t[1] = A - r31;
    t[2] = A - r31 - c0 + xr0;
    t[3] = A - c31;
    t[4] = A;
    t[5] = A - c0;
    t[6] = A - r0 - c31 + x0c;
    t[7] = A - r0;
    t[8] = A - r0 - c0 + x00;
  }
}

// ---------------- SE dot ----------------
__global__ __launch_bounds__(256) void se_dot_kernel(const float* __restrict__ T,
    const float* __restrict__ conv1_w, const float* __restrict__ w_down, float* __restrict__ ydot) {
  int bg = blockIdx.x;
  int g = bg & 3;
  int t = threadIdx.x;
  int cout = t >> 1, half = t & 1;
  const float* wp = conv1_w + (size_t)(g * NC + cout) * 1152 + half * 576;
  const float* tp = T + (size_t)bg * 1152 + half * 576;
  float acc = 0;
  for (int i = 0; i < 576; ++i) acc += wp[i] * tp[i];
  acc *= w_down[g * NC + cout];
#pragma unroll
  for (int off = 32; off > 0; off >>= 1) acc += __shfl_down(acc, off);
  __shared__ float red[4];
  if ((t & 63) == 0) red[t >> 6] = acc;
  __syncthreads();
  if (t == 0) ydot[bg] = red[0] + red[1] + red[2] + red[3];
}

// ---------------- tiny SE MLP ----------------
__global__ void mlp_kernel(const float* __restrict__ ydot, const float* __restrict__ b_down,
    const float* __restrict__ w1, const float* __restrict__ b1,
    const float* __restrict__ w2, const float* __restrict__ b2, float* __restrict__ wgt) {
  int b = threadIdx.x;
  if (b >= NB) return;
  float y[4];
#pragma unroll
  for (int g = 0; g < 4; ++g) y[g] = ydot[b * 4 + g] * (1.f / 1024.f) + b_down[g];
  float y1[16];
#pragma unroll
  for (int i = 0; i < 16; ++i) {
    float a = b1[i];
#pragma unroll
    for (int g = 0; g < 4; ++g) a += y[g] * w1[i * 4 + g];
    y1[i] = gelu_f(a);
  }
#pragma unroll
  for (int g = 0; g < 4; ++g) {
    float a = b2[g];
#pragma unroll
    for (int i = 0; i < 16; ++i) a += y1[i] * w2[g * 16 + i];
    wgt[b * 4 + g] = sigmoid_f(a);
  }
}

// ---------------- G ----------------
__global__ __launch_bounds__(128) void g_kernel(const float* __restrict__ conv1_w,
    const float* __restrict__ w_gk, float* __restrict__ G) {
  int blk = blockIdx.x;
  int w = blk >> 7;
  int q = blk & 127;
  int p = threadIdx.x;
  __shared__ float wg[128];
  wg[p] = w_gk[(size_t)q * 512 + w * NC + p];
  __syncthreads();
  const float* cw = conv1_w + (size_t)(w * NC + p) * 1152;
  float acc[9] = {0, 0, 0, 0, 0, 0, 0, 0, 0};
  for (int cin = 0; cin < 128; ++cin) {
    float s = wg[cin];
#pragma unroll
    for (int ij = 0; ij < 9; ++ij) acc[ij] += s * cw[cin * 9 + ij];
  }
  float* gp = G + ((size_t)blk * 128 + p) * 9;
#pragma unroll
  for (int ij = 0; ij < 9; ++ij) gp[ij] = acc[ij];
}

// ---------------- sfus ----------------
__global__ void sfus_kernel(const float* __restrict__ w_fus, float* __restrict__ sfus) {
  int o = threadIdx.x;
  float s = 0;
  for (int p = 0; p < 128; ++p) s += w_fus[(size_t)o * 640 + 512 + p];
  sfus[o] = s;
}

// ---------------- AW ----------------
__global__ __launch_bounds__(128) void aw_kernel(const float* __restrict__ conv1_w,
    const float* __restrict__ w_fus, const float* __restrict__ G, float* __restrict__ AW) {
  int blk = blockIdx.x;
  int w = blk >> 7;
  int o = blk & 127;
  int q = threadIdx.x;
  __shared__ float wf1[128], wf2[128];
  wf1[q] = w_fus[(size_t)o * 640 + w * NC + q];
  wf2[q] = w_fus[(size_t)o * 640 + 512 + q];
  __syncthreads();
  float acc[9] = {0, 0, 0, 0, 0, 0, 0, 0, 0};
  for (int c = 0; c < 128; ++c) {
    const float* cw = conv1_w + ((size_t)(w * NC + c) * NC + q) * 9;
    float s = wf1[c];
#pragma unroll
    for (int ij = 0; ij < 9; ++ij) acc[ij] += s * cw[ij];
  }
  const float* gq = G + (size_t)(w * NC + q) * 128 * 9;
  for (int p = 0; p < 128; ++p) {
    float s = wf2[p];
#pragma unroll
    for (int ij = 0; ij < 9; ++ij) acc[ij] += s * gq[p * 9 + ij];
  }
  float* ap = AW + ((size_t)(w * NC + o) * NC + q) * 9;
#pragma unroll
  for (int ij = 0; ij < 9; ++ij) ap[ij] = acc[ij];
}

// ---------------- M -> bf16, layout [b][ij][oc][q] with q-chunk XOR-swizzle (key oc&7) ----------------
__global__ __launch_bounds__(128) void m_kernel(const float* __restrict__ AW,
    const float* __restrict__ wgt, const float* __restrict__ sfus,
    const float* __restrict__ b_gk, unsigned short* __restrict__ Mb) {
  int blk = blockIdx.x;           // b*128 + o
  int b = blk >> 7;
  int o = blk & 127;
  int q = threadIdx.x;
  float w0 = wgt[b * 4 + 0], w1v = wgt[b * 4 + 1], w2v = wgt[b * 4 + 2], w3v = wgt[b * 4 + 3];
  float a3 = sfus[o] * b_gk[q];
  const size_t st = (size_t)NC * NC * 9;
  int qswz = (q & 7) | (((q >> 3) ^ (o & 7)) << 3);
#pragma unroll
  for (int ij = 0; ij < 9; ++ij) {
    size_t idx = ((size_t)o * NC + q) * 9 + ij;
    float m = w0 * AW[idx] + w1v * AW[idx + st] + w2v * AW[idx + 2 * st]
            + w3v * AW[idx + 3 * st] + a3;
    Mb[(((size_t)(b * 9 + ij) * NC + o) * NC) + qswz] = f2bf(m);
  }
}

// ---------------- prep weights to bf16 swizzled ----------------
__global__ __launch_bounds__(256) void prep_w1_kernel(const float* __restrict__ w, unsigned short* __restrict__ o) {
  int idx = blockIdx.x * 256 + threadIdx.x;   // 8192: n(512) x c16(16)
  int n = idx >> 4, c16 = idx & 15;
  const float4 a = *(const float4*)(w + (size_t)n * 128 + c16 * 8);
  const float4 b = *(const float4*)(w + (size_t)n * 128 + c16 * 8 + 4);
  unsigned int p0 = (unsigned int)f2bf(a.x) | ((unsigned int)f2bf(a.y) << 16);
  unsigned int p1 = (unsigned int)f2bf(a.z) | ((unsigned int)f2bf(a.w) << 16);
  unsigned int p2 = (unsigned int)f2bf(b.x) | ((unsigned int)f2bf(b.y) << 16);
  unsigned int p3 = (unsigned int)f2bf(b.z) | ((unsigned int)f2bf(b.w) << 16);
  uint4 v = make_uint4(p0, p1, p2, p3);
  *(uint4*)((char*)o + (size_t)n * 256 + ((c16 ^ (n & 7)) << 4)) = v;
}
__global__ __launch_bounds__(256) void prep_w2_kernel(const float* __restrict__ w, unsigned short* __restrict__ o) {
  int idx = blockIdx.x * 256 + threadIdx.x;   // 8192: kt(4) x c(128) x c16(16)
  int kt = idx >> 11, c = (idx >> 4) & 127, c16 = idx & 15;
  const float* s = w + (size_t)c * NHID + kt * 128 + c16 * 8;
  const float4 a = *(const float4*)(s);
  const float4 b = *(const float4*)(s + 4);
  unsigned int p0 = (unsigned int)f2bf(a.x) | ((unsigned int)f2bf(a.y) << 16);
  unsigned int p1 = (unsigned int)f2bf(a.z) | ((unsigned int)f2bf(a.w) << 16);
  unsigned int p2 = (unsigned int)f2bf(b.x) | ((unsigned int)f2bf(b.y) << 16);
  unsigned int p3 = (unsigned int)f2bf(b.z) | ((unsigned int)f2bf(b.w) << 16);
  uint4 v = make_uint4(p0, p1, p2, p3);
  *(uint4*)((char*)o + (size_t)(kt * 128 + c) * 256 + ((c16 ^ (c & 7)) << 4)) = v;
}

// ---------------- MFMA dynamic 3x3 conv: block = 2 waves, 64 spatial(8x8) x 128 oc ----------------
__global__ __launch_bounds__(128) void conv_kernel(const float* __restrict__ x0,
    const unsigned short* __restrict__ xln, const unsigned short* __restrict__ Mb,
    const float* __restrict__ b_fus, float* __restrict__ xout) {
  __shared__ uint4 XT[1600];   // 10x10 cells x 128 q bf16, swizzled (25.6KB)
  __shared__ uint4 MT[2048];   // 128 oc x 128 q bf16, swizzled (32KB)
  int bx = blockIdx.x;
  int b = bx >> 6, tile = bx & 63;
  int by = (tile >> 3) * 8, bxc = (tile & 7) * 8;
  int tid = threadIdx.x, wv = tid >> 6, l = tid & 63;
  // stage XT (reg-staged, swizzled writes, zero halo)
  for (int i = tid; i < 1600; i += 128) {
    int cell = i >> 4, c16 = i & 15;
    int pr = cell / 10, pc = cell - pr * 10;
    int gy = by + pr - 1, gx = bxc + pc - 1;
    uint4 v = make_uint4(0, 0, 0, 0);
    if ((unsigned)gy < 64u && (unsigned)gx < 64u)
      v = *(const uint4*)(xln + (((size_t)b * NL + gy * 64 + gx) * NC + c16 * 8));
    *(uint4*)((char*)XT + cell * 256 + ((c16 ^ (cell & 7)) << 4)) = v;
  }
  const char* mg = (const char*)Mb + (size_t)b * 9 * 32768;
  for (int i = wv; i < 32; i += 2) gld16(mg + (i << 10) + l * 16, (char*)MT + (i << 10));
  __syncthreads();

  const f32x4 zero = {0.f, 0.f, 0.f, 0.f};
  f32x4 acc[2][8];
#pragma unroll
  for (int mt = 0; mt < 2; ++mt)
#pragma unroll
    for (int nt = 0; nt < 8; ++nt) acc[mt][nt] = zero;

  for (int ij = 0; ij < 9; ++ij) {
    int di = ij / 3, dj = ij - di * 3;
    bf16x8 af[2][4];
#pragma unroll
    for (int mt = 0; mt < 2; ++mt) {
      int sp = mt * 16 + (l & 15);
      int cell = (wv * 4 + (sp >> 3) + di) * 10 + (sp & 7) + dj;
#pragma unroll
      for (int ks = 0; ks < 4; ++ks) {
        int c16 = ks * 4 + (l >> 4);
        af[mt][ks] = *(const bf16x8*)((const char*)XT + cell * 256 + ((c16 ^ (cell & 7)) << 4));
      }
    }
#pragma unroll
    for (int nt = 0; nt < 8; ++nt) {
      int oc = nt * 16 + (l & 15);
      bf16x8 bq[4];
#pragma unroll
      for (int ks = 0; ks < 4; ++ks) {
        int c16 = ks * 4 + (l >> 4);
        bq[ks] = *(const bf16x8*)((const char*)MT + oc * 256 + ((c16 ^ (oc & 7)) << 4));
      }
#pragma unroll
      for (int ks = 0; ks < 4; ++ks)
#pragma unroll
        for (int mt = 0; mt < 2; ++mt)
          acc[mt][nt] = __builtin_amdgcn_mfma_f32_16x16x32_bf16(af[mt][ks], bq[ks], acc[mt][nt], 0, 0, 0);
    }
    __syncthreads();
    if (ij < 8) {
      const char* mg2 = mg + (size_t)(ij + 1) * 32768;
      for (int i = wv; i < 32; i += 2) gld16(mg2 + (i << 10) + l * 16, (char*)MT + (i << 10));
    }
    __syncthreads();
  }
  // epilogue: residual + bias
#pragma unroll
  for (int mt = 0; mt < 2; ++mt)
#pragma unroll
    for (int nt = 0; nt < 8; ++nt) {
      int oc = nt * 16 + (l & 15);
#pragma unroll
      for (int r2 = 0; r2 < 4; ++r2) {
        int m2 = (l >> 4) * 4 + r2;
        int sp = mt * 16 + m2;
        int gy = by + wv * 4 + (sp >> 3), gx = bxc + (sp & 7);
        size_t gi = ((size_t)b * NL + gy * 64 + gx) * NC + oc;
        xout[gi] = x0[gi] + acc[mt][nt][r2] + b_fus[oc];
      }
    }
}

// ---------------- MFMA lin1 + gelu: block = 2 waves, 64 rows x 128 cols ----------------
__global__ __launch_bounds__(128) void lin1_kernel(const unsigned short* __restrict__ xa,
    const unsigned short* __restrict__ wb, const float* __restrict__ bias,
    unsigned short* __restrict__ h1p0, unsigned short* __restrict__ h1p123) {
  __shared__ uint4 XA[1024];   // 64 x 128 bf16 (16KB)
  __shared__ uint4 XB[2048];   // 128 x 128 bf16 (32KB)
  int bx = blockIdx.x;
  int cb = bx & 3;
  size_t rb = (size_t)(bx >> 2) * 64;
  int tid = threadIdx.x, wv = tid >> 6, l = tid & 63;
  const char* ga = (const char*)xa + rb * 256;
  const char* gb = (const char*)wb + (size_t)cb * 32768;
  for (int i = wv; i < 16; i += 2) gld16(ga + (i << 10) + l * 16, (char*)XA + (i << 10));
  for (int i = wv; i < 32; i += 2) gld16(gb + (i << 10) + l * 16, (char*)XB + (i << 10));
  __syncthreads();
  const f32x4 zero = {0.f, 0.f, 0.f, 0.f};
  f32x4 acc[2][8];
#pragma unroll
  for (int mt = 0; mt < 2; ++mt)
#pragma unroll
    for (int nt = 0; nt < 8; ++nt) acc[mt][nt] = zero;
  bf16x8 af[2][4];
#pragma unroll
  for (int mt = 0; mt < 2; ++mt) {
    int r = wv * 32 + mt * 16 + (l & 15);
#pragma unroll
    for (int ks = 0; ks < 4; ++ks) {
      int c16 = ks * 4 + (l >> 4);
      af[mt][ks] = *(const bf16x8*)((const char*)XA + r * 256 + ((c16 ^ (r & 7)) << 4));
    }
  }
#pragma unroll
  for (int nt = 0; nt < 8; ++nt) {
    int n = nt * 16 + (l & 15);
    bf16x8 bq[4];
#pragma unroll
    for (int ks = 0; ks < 4; ++ks) {
      int c16 = ks * 4 + (l >> 4);
      bq[ks] = *(const bf16x8*)((const char*)XB + n * 256 + ((c16 ^ (n & 7)) << 4));
    }
#pragma unroll
    for (int ks = 0; ks < 4; ++ks)
#pragma unroll
      for (int mt = 0; mt < 2; ++mt)
        acc[mt][nt] = __builtin_amdgcn_mfma_f32_16x16x32_bf16(af[mt][ks], bq[ks], acc[mt][nt], 0, 0, 0);
  }
  unsigned short* hp = (cb == 0) ? h1p0 : h1p123 + (size_t)(cb - 1) * 4194304;
#pragma unroll
  for (int mt = 0; mt < 2; ++mt)
#pragma unroll
    for (int nt = 0; nt < 8; ++nt) {
      int n = nt * 16 + (l & 15);
      float bsv = bias[cb * 128 + n];
#pragma unroll
      for (int r2 = 0; r2 < 4; ++r2) {
        int m2 = (l >> 4) * 4 + r2;
        size_t row = rb + wv * 32 + mt * 16 + m2;
        hp[row * 128 + n] = f2bf(gelu_f(acc[mt][nt][r2] + bsv));
      }
    }
}

// ---------------- depthwise 3x3 + gelu, bf16 in / swizzled bf16 out ----------------
__global__ __launch_bounds__(256) void dw_kernel(const unsigned short* __restrict__ h1p0,
    const unsigned short* __restrict__ h1p123, const float* __restrict__ dw_w,
    const float* __restrict__ dw_b, unsigned short* __restrict__ h2p0,
    unsigned short* __restrict__ h2p123) {
  int bx = blockIdx.x;
  int p = bx >> 11, c16 = (bx >> 7) & 15, rblk = bx & 127;
  int row = rblk * 256 + threadIdx.x;
  const unsigned short* h1p = p ? (h1p123 + (size_t)(p - 1) * 4194304) : h1p0;
  unsigned short* h2p = p ? (h2p123 + (size_t)(p - 1) * 4194304) : h2p0;
  int xw = row & 63, yy = (row >> 6) & 63;
  int hc0 = p * 128 + c16 * 8;
  float acc[8];
#pragma unroll
  for (int j = 0; j < 8; ++j) acc[j] = dw_b[hc0 + j];
#pragma unroll
  for (int dy = -1; dy <= 1; ++dy) {
    if ((unsigned)(yy + dy) >= 64u) continue;
#pragma unroll
    for (int dx = -1; dx <= 1; ++dx) {
      if ((unsigned)(xw + dx) >= 64u) continue;
      int tap = (dy + 1) * 3 + (dx + 1);
      const uint4 v = *(const uint4*)(h1p + (size_t)(row + dy * 64 + dx) * 128 + c16 * 8);
      acc[0] += dw_w[(hc0 + 0) * 9 + tap] * bflo(v.x);
      acc[1] += dw_w[(hc0 + 1) * 9 + tap] * bfhi(v.x);
      acc[2] += dw_w[(hc0 + 2) * 9 + tap] * bflo(v.y);
      acc[3] += dw_w[(hc0 + 3) * 9 + tap] * bfhi(v.y);
      acc[4] += dw_w[(hc0 + 4) * 9 + tap] * bflo(v.z);
      acc[5] += dw_w[(hc0 + 5) * 9 + tap] * bfhi(v.z);
      acc[6] += dw_w[(hc0 + 6) * 9 + tap] * bflo(v.w);
      acc[7] += dw_w[(hc0 + 7) * 9 + tap] * bfhi(v.w);
    }
  }
  unsigned int o0 = (unsigned int)f2bf(gelu_f(acc[0])) | ((unsigned int)f2bf(gelu_f(acc[1])) << 16);
  unsigned int o1 = (unsigned int)f2bf(gelu_f(acc[2])) | ((unsigned int)f2bf(gelu_f(acc[3])) << 16);
  unsigned int o2 = (unsigned int)f2bf(gelu_f(acc[4])) | ((unsigned int)f2bf(gelu_f(acc[5])) << 16);
  unsigned int o3 = (unsigned int)f2bf(gelu_f(acc[6])) | ((unsigned int)f2bf(gelu_f(acc[7])) << 16);
  *(uint4*)(h2p + (size_t)row * 128 + ((c16 ^ (row & 7)) << 3)) = make_uint4(o0, o1, o2, o3);
}

// ---------------- MFMA lin2 + residual + bias: block = 2 waves, 64 rows x 128 cols, K=512 ----------------
__global__ __launch_bounds__(128) void lin2_kernel(const unsigned short* __restrict__ h2p0,
    const unsigned short* __restrict__ h2p123, const unsigned short* __restrict__ wb,
    const float* __restrict__ bias, const float* __restrict__ xres, float* __restrict__ out) {
  __shared__ uint4 XA[1024];
  __shared__ uint4 XB[2048];
  size_t rb = (size_t)blockIdx.x * 64;
  int tid = threadIdx.x, wv = tid >> 6, l = tid & 63;
  const f32x4 zero = {0.f, 0.f, 0.f, 0.f};
  f32x4 acc[2][8];
#pragma unroll
  for (int mt = 0; mt < 2; ++mt)
#pragma unroll
    for (int nt = 0; nt < 8; ++nt) acc[mt][nt] = zero;
  for (int kt = 0; kt < 4; ++kt) {
    if (kt) __syncthreads();
    const unsigned short* hp = (kt == 0) ? h2p0 : h2p123 + (size_t)(kt - 1) * 4194304;
    const char* ga = (const char*)hp + rb * 256;
    const char* gb = (const char*)wb + (size_t)kt * 32768;
    for (int i = wv; i < 16; i += 2) gld16(ga + (i << 10) + l * 16, (char*)XA + (i << 10));
    for (int i = wv; i < 32; i += 2) gld16(gb + (i << 10) + l * 16, (char*)XB + (i << 10));
    __syncthreads();
    bf16x8 af[2][4];
#pragma unroll
    for (int mt = 0; mt < 2; ++mt) {
      int r = wv * 32 + mt * 16 + (l & 15);
#pragma unroll
      for (int ks = 0; ks < 4; ++ks) {
        int c16 = ks * 4 + (l >> 4);
        af[mt][ks] = *(const bf16x8*)((const char*)XA + r * 256 + ((c16 ^ (r & 7)) << 4));
      }
    }
#pragma unroll
    for (int nt = 0; nt < 8; ++nt) {
      int n = nt * 16 + (l & 15);
      bf16x8 bq[4];
#pragma unroll
      for (int ks = 0; ks < 4; ++ks) {
        int c16 = ks * 4 + (l >> 4);
        bq[ks] = *(const bf16x8*)((const char*)XB + n * 256 + ((c16 ^ (n & 7)) << 4));
      }
#pragma unroll
      for (int ks = 0; ks < 4; ++ks)
#pragma unroll
        for (int mt = 0; mt < 2; ++mt)
          acc[mt][nt] = __builtin_amdgcn_mfma_f32_16x16x32_bf16(af[mt][ks], bq[ks], acc[mt][nt], 0, 0, 0);
    }
  }
#pragma unroll
  for (int mt = 0; mt < 2; ++mt)
#pragma unroll
    for (int nt = 0; nt < 8; ++nt) {
      int n = nt * 16 + (l & 15);
      float bsv = bias[n];
#pragma unroll
      for (int r2 = 0; r2 < 4; ++r2) {
        int m2 = (l >> 4) * 4 + r2;
        size_t row = rb + wv * 32 + mt * 16 + m2;
        size_t gi = row * NC + n;
        out[gi] = xres[gi] + acc[mt][nt][r2] + bsv;
      }
    }
}

extern "C" void kernel_launch(void* const* d_in, const int* in_sizes, int n_in,
                              void* d_out, int out_size, void* d_ws, size_t ws_size,
                              hipStream_t stream) {
  (void)in_sizes; (void)n_in; (void)out_size; (void)ws_size;
  const float* x       = (const float*)d_in[0];
  const float* ln1_g   = (const float*)d_in[1];
  const float* ln1_b   = (const float*)d_in[2];
  const float* conv1_w = (const float*)d_in[3];
  const float* w_down  = (const float*)d_in[4];
  const float* b_down  = (const float*)d_in[5];
  const float* w1      = (const float*)d_in[6];
  const float* b1      = (const float*)d_in[7];
  const float* w2      = (const float*)d_in[8];
  const float* b2      = (const float*)d_in[9];
  const float* w_gk    = (const float*)d_in[10];
  const float* b_gk    = (const float*)d_in[11];
  const float* w_fus   = (const float*)d_in[12];
  const float* b_fus   = (const float*)d_in[13];
  const float* ln2_g   = (const float*)d_in[14];
  const float* ln2_b   = (const float*)d_in[15];
  const float* lin1_w  = (const float*)d_in[16];
  const float* lin1_b  = (const float*)d_in[17];
  const float* dw_w    = (const float*)d_in[18];
  const float* dw_b    = (const float*)d_in[19];
  const float* lin2_w  = (const float*)d_in[20];
  const float* lin2_b  = (const float*)d_in[21];
  float* out = (float*)d_out;
  char* ws = (char*)d_ws;

  // byte offsets (all 256B aligned); total ~87.2 MiB
  float*          xatt    = (float*)(ws);                    // 16,777,216
  float*          Tb      = (float*)(ws + 16777216);         // 147,456
  float*          ydot    = (float*)(ws + 16924672);         // 512
  float*          wgtb    = (float*)(ws + 16925184);         // 512
  float*          sfus    = (float*)(ws + 16925696);         // 512
  float*          Gb      = (float*)(ws + 16926208);         // 2,359,296
  float*          AWb     = (float*)(ws + 19285504);         // 2,359,296
  unsigned short* M_bf    = (unsigned short*)(ws + 21644800);// 2,359,296
  unsigned short* w1_bf   = (unsigned short*)(ws + 24004096);// 131,072
  unsigned short* w2_bf   = (unsigned short*)(ws + 24135168);// 131,072
  unsigned short* xln_bf  = (unsigned short*)(ws + 24266240);// 8,388,608 (reused as h1 plane0)
  unsigned short* xln2_bf = (unsigned short*)(ws + 32654848);// 8,388,608 (reused as h2 plane0)
  unsigned short* h1p123  = (unsigned short*)(ws + 41043456);// 25,165,824
  unsigned short* h2p123  = (unsigned short*)(ws + 66209280);// 25,165,824  (end 91,375,104)

  ln_kernel<false><<<8192, 256, 0, stream>>>(x, ln1_g, ln1_b, xln_bf);
  prep_w1_kernel<<<32, 256, 0, stream>>>(lin1_w, w1_bf);
  prep_w2_kernel<<<32, 256, 0, stream>>>(lin2_w, w2_bf);
  t_kernel<<<4096, 64, 0, stream>>>(xln_bf, Tb);
  se_dot_kernel<<<32, 256, 0, stream>>>(Tb, conv1_w, w_down, ydot);
  mlp_kernel<<<1, 64, 0, stream>>>(ydot, b_down, w1, b1, w2, b2, wgtb);
  g_kernel<<<512, 128, 0, stream>>>(conv1_w, w_gk, Gb);
  sfus_kernel<<<1, 128, 0, stream>>>(w_fus, sfus);
  aw_kernel<<<512, 128, 0, stream>>>(conv1_w, w_fus, Gb, AWb);
  m_kernel<<<1024, 128, 0, stream>>>(AWb, wgtb, sfus, b_gk, M_bf);
  conv_kernel<<<512, 128, 0, stream>>>(x, xln_bf, M_bf, b_fus, xatt);
  ln_kernel<true><<<8192, 256, 0, stream>>>(xatt, ln2_g, ln2_b, xln2_bf);
  lin1_kernel<<<2048, 128, 0, stream>>>(xln2_bf, w1_bf, lin1_b, xln_bf /*h1 p0*/, h1p123);
  dw_kernel<<<8192, 256, 0, stream>>>(xln_bf /*h1 p0*/, h1p123, dw_w, dw_b,
                                      xln2_bf /*h2 p0*/, h2p123);
  lin2_kernel<<<512, 128, 0, stream>>>(xln2_bf /*h2 p0*/, h2p123, w2_bf, lin2_b, xatt, out);
}